// Round 2
// baseline (232.048 us; speedup 1.0000x reference)
//
#include <hip/hip_runtime.h>

#define BS    16
#define NPTS  4096
#define CH    32
#define HID   16
#define NORB  64
#define NTHR  1024
#define PTS_PER_PASS (NTHR / 8)        // 128 points in flight per pass
#define NPASS (NPTS / PTS_PER_PASS)    // 32
#define CHUNK 8                        // passes prefetched per iteration

// Fully fused, ZERO-workspace kernel: one block per batch element.
// Rationale: the harness re-poisons the full 256 MiB workspace inside the
// timed region (~40 us per fill at 82% HBM peak — the top-5 dispatches in
// round-0 rocprof were all fillBufferAligned). Avoiding d_ws entirely removes
// that dependency. The only cross-block communication in the algorithm was the
// partial-aggregate buffer; owning a whole batch element per block removes it.
// (Round 1 was an infra failure — "container failed twice", no kernel signal —
// this is a clean resubmission of the same kernel.)
__global__ __launch_bounds__(NTHR) void gigp_fused(
    const float* __restrict__ coords, // [BS][N][2][2]
    const float* __restrict__ vals,   // [BS][N][CH]
    const int*   __restrict__ mask,   // [BS][N]
    const float* __restrict__ W1, const float* __restrict__ b1,
    const float* __restrict__ W2, const float* __restrict__ b2,
    const float* __restrict__ W3, const float* __restrict__ b3,
    float*       __restrict__ out)    // [BS]
{
    // +1 pad: atomic phase and MLP phase both spread banks by (k+c)%32
    __shared__ float agg[NORB][CH + 1];
    // MLP weights staged to LDS so the 64-thread tail doesn't serialize on
    // global loads: [0,512)=W1, [512,528)=b1, [528,784)=W2, [784,800)=b2,
    // [800,816)=W3, [816]=b3
    __shared__ float wbuf[832];

    const int tid = threadIdx.x;
    const int b   = blockIdx.x;

    for (int i = tid; i < NORB * (CH + 1); i += NTHR)
        (&agg[0][0])[i] = 0.0f;

    // one pass, 1024 threads covers all 817 weights
    if      (tid < 512) wbuf[tid] = W1[tid];
    else if (tid < 528) wbuf[tid] = b1[tid - 512];
    else if (tid < 784) wbuf[tid] = W2[tid - 528];
    else if (tid < 800) wbuf[tid] = b2[tid - 784];
    else if (tid < 816) wbuf[tid] = W3[tid - 800];
    else if (tid == 816) wbuf[816] = b3[0];

    const int c4 = tid & 7;        // which float4 of the 32 channels
    const int pl = tid >> 3;       // point lane within a pass
    const float4* vals4 = (const float4*)vals;

    __syncthreads();   // LDS zeroing + weight staging done

    #pragma unroll 1
    for (int pass0 = 0; pass0 < NPASS; pass0 += CHUNK) {
        int    kk[CHUNK];
        int    mm[CHUNK];
        float4 vv[CHUNK];
        #pragma unroll
        for (int j = 0; j < CHUNK; ++j) {
            const int n  = (pass0 + j) * PTS_PER_PASS + pl;
            const int gi = b * NPTS + n;
            kk[j] = (int)coords[(size_t)gi * 4 + 3]; // coords[b][n][1][1]
            mm[j] = mask[gi];
            vv[j] = vals4[(size_t)gi * 8 + c4];
        }
        #pragma unroll
        for (int j = 0; j < CHUNK; ++j) {
            if (mm[j]) {
                const int k = kk[j];
                atomicAdd(&agg[k][c4 * 4 + 0], vv[j].x);
                atomicAdd(&agg[k][c4 * 4 + 1], vv[j].y);
                atomicAdd(&agg[k][c4 * 4 + 2], vv[j].z);
                atomicAdd(&agg[k][c4 * 4 + 3], vv[j].w);
            }
        }
    }
    __syncthreads();

    if (tid < NORB) {
        const int k = tid;
        const float* Wl1 = wbuf;
        const float* bl1 = wbuf + 512;
        const float* Wl2 = wbuf + 528;
        const float* bl2 = wbuf + 784;
        const float* Wl3 = wbuf + 800;
        const float  bl3 = wbuf[816];

        float chsum = 0.0f;
        #pragma unroll
        for (int cc = 0; cc < CH; ++cc) chsum += agg[k][cc];

        float h1[HID];
        #pragma unroll
        for (int j = 0; j < HID; ++j) h1[j] = bl1[j];
        #pragma unroll
        for (int cc = 0; cc < CH; ++cc) {
            const float x = agg[k][cc];
            #pragma unroll
            for (int j = 0; j < HID; ++j)
                h1[j] += x * Wl1[cc * HID + j];
        }
        #pragma unroll
        for (int j = 0; j < HID; ++j) h1[j] = h1[j] > 0.0f ? h1[j] : 0.0f;

        float h2[HID];
        #pragma unroll
        for (int j = 0; j < HID; ++j) h2[j] = bl2[j];
        #pragma unroll
        for (int i = 0; i < HID; ++i) {
            const float x = h1[i];
            #pragma unroll
            for (int j = 0; j < HID; ++j)
                h2[j] += x * Wl2[i * HID + j];
        }
        float o = bl3;
        #pragma unroll
        for (int i = 0; i < HID; ++i) {
            const float x = h2[i] > 0.0f ? h2[i] : 0.0f;
            o += x * Wl3[i];
        }
        o = (chsum == 0.0f) ? 0.0f : o;

        // one-wave reduction over 64 orbits (tid<64 is wave 0)
        #pragma unroll
        for (int off = 32; off > 0; off >>= 1)
            o += __shfl_down(o, off);
        if (k == 0) out[b] = o;
    }
}

extern "C" void kernel_launch(void* const* d_in, const int* in_sizes, int n_in,
                              void* d_out, int out_size, void* d_ws, size_t ws_size,
                              hipStream_t stream) {
    const float* coords = (const float*)d_in[0];
    const float* vals   = (const float*)d_in[1];
    const int*   mask   = (const int*)d_in[2];
    const float* W1     = (const float*)d_in[3];
    const float* b1     = (const float*)d_in[4];
    const float* W2     = (const float*)d_in[5];
    const float* b2     = (const float*)d_in[6];
    const float* W3     = (const float*)d_in[7];
    const float* b3     = (const float*)d_in[8];
    float* out = (float*)d_out;
    // NOTE: d_ws intentionally unused — workspace use triggers a 256 MiB
    // re-poison fill (~40+ us at HBM peak) inside the timed region.

    gigp_fused<<<BS, NTHR, 0, stream>>>(coords, vals, mask,
                                        W1, b1, W2, b2, W3, b3, out);
}

// Round 3
// 98.048 us; speedup vs baseline: 2.3667x; 2.3667x over previous
//
#include <hip/hip_runtime.h>

#define BS     16
#define NPTS   4096
#define CH     32
#define HID    16
#define NORB   64
#define SLICES 16
#define PPB    (NPTS / SLICES)   // 256 points per block

// Stage A: deterministic scan aggregation, NO atomics.
// grid = BS*SLICES = 256 blocks x 256 threads (1 block/CU).
// Each thread owns (orbit k = tid>>2, channel group c0 = (tid&3)*8) and
// accumulates in registers while scanning the block's 256 keys via readlane.
// LDS-atomic postmortem (round 2): ds_add_f32 measured ~0.34 scalar-ops/cycle
// — 2M scalar atomics is ~160us on 16 CUs. Scan does 0 atomics.
__global__ __launch_bounds__(256) void gigp_agg(
    const float* __restrict__ coords, // [BS][N][2][2]
    const float* __restrict__ vals,   // [BS][N][CH]
    const int*   __restrict__ mask,   // [BS][N]
    float*       __restrict__ part)   // [BS][SLICES][NORB][CH]
{
    __shared__ float vlds[PPB][CH];   // 32 KB, row = point, conflict-free hit reads
    __shared__ int   klds[PPB];       // mask folded in (NORB = masked-out sentinel)

    const int tid   = threadIdx.x;
    const int b     = blockIdx.x >> 4;          // / SLICES
    const int slice = blockIdx.x & (SLICES - 1);
    const size_t gbase = (size_t)b * NPTS + slice * PPB;

    // coalesced stage of the 256-point vals chunk: 2048 float4
    const float4* v4  = (const float4*)vals + gbase * (CH / 4);
    float4*       vl4 = (float4*)&vlds[0][0];
    #pragma unroll
    for (int i = 0; i < PPB * CH / (4 * 256); ++i)   // 8 iters
        vl4[tid + i * 256] = v4[tid + i * 256];

    {   // keys: one per thread
        const size_t gi = gbase + tid;
        const int k = (int)coords[gi * 4 + 3];       // coords[b][n][1][1]
        klds[tid] = mask[gi] ? k : NORB;             // sentinel never matches
    }
    __syncthreads();

    const int myk  = tid >> 2;
    const int c0   = (tid & 3) * 8;
    const int lane = tid & 63;
    // wave w owns contiguous orbit range [wo, wo+16): cheap scalar pre-filter
    const int wo_s = __builtin_amdgcn_readfirstlane((tid >> 6) << 4);

    float acc[8] = {0, 0, 0, 0, 0, 0, 0, 0};

    for (int base = 0; base < PPB; base += 64) {
        const int kreg = klds[base + lane];          // 64 keys into wave regs
        #pragma unroll 8
        for (int j = 0; j < 64; ++j) {
            const int kn = __builtin_amdgcn_readlane(kreg, j);  // SGPR
            if ((unsigned)(kn - wo_s) < 16u) {       // scalar range test
                if (kn == myk) {                     // exactly 4 lanes hit
                    const float4 u0 = *(const float4*)&vlds[base + j][c0];
                    const float4 u1 = *(const float4*)&vlds[base + j][c0 + 4];
                    acc[0] += u0.x; acc[1] += u0.y; acc[2] += u0.z; acc[3] += u0.w;
                    acc[4] += u1.x; acc[5] += u1.y; acc[6] += u1.z; acc[7] += u1.w;
                }
            }
        }
    }

    // deterministic partial store: thread owns float4 pair {fi, fi+1}
    float4* dst = (float4*)(part + ((size_t)b * SLICES + slice) * NORB * CH);
    const int fi = myk * 8 + (tid & 3) * 2;
    dst[fi]     = make_float4(acc[0], acc[1], acc[2], acc[3]);
    dst[fi + 1] = make_float4(acc[4], acc[5], acc[6], acc[7]);
}

// Stage B: reduce 16 slices + MLP. grid = BS blocks x 256 threads.
// Weights staged to LDS by all 256 threads (round-0's tid<64 tail cold-missed
// ~52 cache lines serially from one wave).
__global__ __launch_bounds__(256) void gigp_mlp(
    const float* __restrict__ part, // [BS][SLICES][NORB][CH]
    const float* __restrict__ W1, const float* __restrict__ b1,
    const float* __restrict__ W2, const float* __restrict__ b2,
    const float* __restrict__ W3, const float* __restrict__ b3,
    float*       __restrict__ out)  // [BS]
{
    __shared__ float agg[NORB][CH + 1];   // +1 pad: MLP reads bank (k+c)%32
    __shared__ float wbuf[832];           // [0,512)W1 [512,528)b1 [528,784)W2
                                          // [784,800)b2 [800,816)W3 [816]b3
    const int b   = blockIdx.x;
    const int tid = threadIdx.x;

    for (int i = tid; i < 817; i += 256) {
        float w;
        if      (i < 512) w = W1[i];
        else if (i < 528) w = b1[i - 512];
        else if (i < 784) w = W2[i - 528];
        else if (i < 800) w = b2[i - 784];
        else if (i < 816) w = W3[i - 800];
        else              w = b3[0];
        wbuf[i] = w;
    }

    const float4* src = (const float4*)(part + (size_t)b * SLICES * NORB * CH);
    float4 a0 = make_float4(0.f, 0.f, 0.f, 0.f);
    float4 a1 = make_float4(0.f, 0.f, 0.f, 0.f);
    #pragma unroll
    for (int s = 0; s < SLICES; ++s) {
        const float4 t0 = src[s * (NORB * CH / 4) + tid];
        const float4 t1 = src[s * (NORB * CH / 4) + tid + 256];
        a0.x += t0.x; a0.y += t0.y; a0.z += t0.z; a0.w += t0.w;
        a1.x += t1.x; a1.y += t1.y; a1.z += t1.z; a1.w += t1.w;
    }
    {
        const int e0 = tid, e1 = tid + 256;
        const int k0 = e0 >> 3, c0 = (e0 & 7) * 4;
        const int k1 = e1 >> 3, c1 = (e1 & 7) * 4;
        agg[k0][c0 + 0] = a0.x; agg[k0][c0 + 1] = a0.y;
        agg[k0][c0 + 2] = a0.z; agg[k0][c0 + 3] = a0.w;
        agg[k1][c1 + 0] = a1.x; agg[k1][c1 + 1] = a1.y;
        agg[k1][c1 + 2] = a1.z; agg[k1][c1 + 3] = a1.w;
    }
    __syncthreads();

    if (tid < NORB) {
        const int k = tid;
        const float* Wl1 = wbuf;
        const float* bl1 = wbuf + 512;
        const float* Wl2 = wbuf + 528;
        const float* bl2 = wbuf + 784;
        const float* Wl3 = wbuf + 800;
        const float  bl3 = wbuf[816];

        float chsum = 0.0f;
        #pragma unroll
        for (int cc = 0; cc < CH; ++cc) chsum += agg[k][cc];

        float h1[HID];
        #pragma unroll
        for (int j = 0; j < HID; ++j) h1[j] = bl1[j];
        #pragma unroll
        for (int cc = 0; cc < CH; ++cc) {
            const float x = agg[k][cc];
            #pragma unroll
            for (int j = 0; j < HID; ++j)
                h1[j] += x * Wl1[cc * HID + j];
        }
        #pragma unroll
        for (int j = 0; j < HID; ++j) h1[j] = h1[j] > 0.0f ? h1[j] : 0.0f;

        float h2[HID];
        #pragma unroll
        for (int j = 0; j < HID; ++j) h2[j] = bl2[j];
        #pragma unroll
        for (int i = 0; i < HID; ++i) {
            const float x = h1[i];
            #pragma unroll
            for (int j = 0; j < HID; ++j)
                h2[j] += x * Wl2[i * HID + j];
        }
        float o = bl3;
        #pragma unroll
        for (int i = 0; i < HID; ++i) {
            const float x = h2[i] > 0.0f ? h2[i] : 0.0f;
            o += x * Wl3[i];
        }
        o = (chsum == 0.0f) ? 0.0f : o;

        #pragma unroll
        for (int off = 32; off > 0; off >>= 1)
            o += __shfl_down(o, off);
        if (k == 0) out[b] = o;
    }
}

extern "C" void kernel_launch(void* const* d_in, const int* in_sizes, int n_in,
                              void* d_out, int out_size, void* d_ws, size_t ws_size,
                              hipStream_t stream) {
    const float* coords = (const float*)d_in[0];
    const float* vals   = (const float*)d_in[1];
    const int*   mask   = (const int*)d_in[2];
    const float* W1     = (const float*)d_in[3];
    const float* b1     = (const float*)d_in[4];
    const float* W2     = (const float*)d_in[5];
    const float* b2     = (const float*)d_in[6];
    const float* W3     = (const float*)d_in[7];
    const float* b3     = (const float*)d_in[8];
    float* out  = (float*)d_out;
    float* part = (float*)d_ws;   // 16*16*64*32*4 = 2 MB, fully overwritten by stage A
    // (Round-2 lesson: the 256 MiB ws poison fill happens UNCONDITIONALLY —
    // avoiding d_ws buys nothing, so use it.)

    gigp_agg<<<BS * SLICES, 256, 0, stream>>>(coords, vals, mask, part);
    gigp_mlp<<<BS, 256, 0, stream>>>(part, W1, b1, W2, b2, W3, b3, out);
}